// Round 7
// baseline (43.897 us; speedup 1.0000x reference)
//
#include <hip/hip_runtime.h>
#include <math.h>

// Problem constants (from reference)
constexpr int BATCH = 512;
constexpr int NC    = 10;
constexpr int RR    = 512;   // NUM_ROUTES
constexpr int CI    = 8;     // IN_CHANNELS
constexpr int CO    = 16;    // OUT_CHANNELS

constexpr int TPB = 64;          // ONE wave per block -> no barriers, no LDS at all
constexpr int RPT = RR / TPB;    // 8 routes per thread

// One block (= one wave) per (b, c). Thread t owns routes t + k*64, k=0..7.
// u_hat[b,c,r,o] = sum_i x[b,r,i] * route_weights[c, b, i, o]
//   (weight's R-slot indexed by b — the reference's broadcasting quirk)
//
// u_hat is never materialized (factored through W):
//   s_j     = (sum_r c_r x_r) . W     -> reduce 8-vector y, not 16-vector
//   u_r . v = x_r . (W v)             -> one shared Wv per iteration
//
// W is WAVE-UNIFORM (depends only on blockIdx) and is read directly from
// global with uniform addresses -> compiler emits s_load into SGPRs via the
// scalar/constant cache. No LDS staging: the LDS pipe carries only the
// ~24 bpermutes/iter of the butterflies (was ~90 heavy DS ops/iter).
__global__ __launch_bounds__(TPB) void caps_route_kernel(
    const float* __restrict__ x,    // (BATCH, RR, CI)
    const float* __restrict__ rw,   // (NC, RR, CI, CO)
    float* __restrict__ out)        // (BATCH, NC, CO)
{
    const int blk  = blockIdx.x;         // 0 .. BATCH*NC-1
    const int b    = blk / NC;
    const int c    = blk - b * NC;
    const int t    = threadIdx.x;        // 0..63 == lane

    // Wave-uniform base for W = route_weights[c, b, :, :]
    const float* __restrict__ Wg = rw + ((size_t)c * RR + b) * (CI * CO);

    // ---- load x rows (coalesced float4, VMEM pipe) ----
    float xs[RPT][CI];
    #pragma unroll
    for (int k = 0; k < RPT; ++k) {
        const float4* xp = (const float4*)(x + ((size_t)b * RR + t + k * TPB) * CI);
        float4 a0 = xp[0], a1 = xp[1];
        xs[k][0]=a0.x; xs[k][1]=a0.y; xs[k][2]=a0.z; xs[k][3]=a0.w;
        xs[k][4]=a1.x; xs[k][5]=a1.y; xs[k][6]=a1.z; xs[k][7]=a1.w;
    }

    float logit[RPT];
    #pragma unroll
    for (int k = 0; k < RPT; ++k) logit[k] = 0.f;

    float num[CO];     // s_j after scaling (all lanes)
    float ks = 0.f;    // squash scale: v[o] = num[o] * ks

    for (int iter = 0; iter < 3; ++iter) {
        // ---- per-thread e-weighted x sum: yl[i] = sum_k e_k xs[k][i] ----
        float yl[CI];
        float den = 0.f;
        if (iter == 0) {
            // b == 0 -> softmax uniform; fold 1/512 in at the scale step
            #pragma unroll
            for (int i = 0; i < CI; ++i) {
                float a = (xs[0][i] + xs[1][i]) + (xs[2][i] + xs[3][i]);
                float d = (xs[4][i] + xs[5][i]) + (xs[6][i] + xs[7][i]);
                yl[i] = a + d;
            }
        } else {
            float e[RPT];
            #pragma unroll
            for (int k = 0; k < RPT; ++k) e[k] = __expf(logit[k]);  // |logit| <~ 44
            den = ((e[0] + e[1]) + (e[2] + e[3])) + ((e[4] + e[5]) + (e[6] + e[7]));
            #pragma unroll
            for (int i = 0; i < CI; ++i) {
                float a = fmaf(e[0], xs[0][i], e[1] * xs[1][i]);
                float d = fmaf(e[2], xs[2][i], e[3] * xs[3][i]);
                float f = fmaf(e[4], xs[4][i], e[5] * xs[5][i]);
                float g = fmaf(e[6], xs[6][i], e[7] * xs[7][i]);
                yl[i] = (a + d) + (f + g);
            }
        }

        // ---- value-split butterfly on 8-vector (10 shuffles) ----
        // KEEP the half matching our lane bit, SEND the other half.
        float s1[4];
        {
            const bool hi = (t & 32) != 0;
            #pragma unroll
            for (int k = 0; k < 4; ++k) {
                float keep = hi ? yl[4 + k] : yl[k];
                float send = hi ? yl[k]     : yl[4 + k];
                s1[k] = keep + __shfl_xor(send, 32, 64);
            }
        }
        float s2[2];
        {
            const bool hi = (t & 16) != 0;
            #pragma unroll
            for (int k = 0; k < 2; ++k) {
                float keep = hi ? s1[2 + k] : s1[k];
                float send = hi ? s1[k]     : s1[2 + k];
                s2[k] = keep + __shfl_xor(send, 16, 64);
            }
        }
        float s3;
        {
            const bool hi = (t & 8) != 0;
            float keep = hi ? s2[1] : s2[0];
            float send = hi ? s2[0] : s2[1];
            s3 = keep + __shfl_xor(send, 8, 64);
        }
        s3 += __shfl_xor(s3, 4, 64);
        s3 += __shfl_xor(s3, 2, 64);
        s3 += __shfl_xor(s3, 1, 64);
        // y[e] now lives (replicated) in lanes 8e..8e+7

        // denominator butterfly -> every lane holds the full sum
        if (iter != 0) {
            den += __shfl_xor(den, 32, 64);
            den += __shfl_xor(den, 16, 64);
            den += __shfl_xor(den,  8, 64);
            den += __shfl_xor(den,  4, 64);
            den += __shfl_xor(den,  2, 64);
            den += __shfl_xor(den,  1, 64);
        } else {
            den = (float)RR;
        }

        // ---- broadcast y[0..7] to all lanes ----
        float y[CI];
        #pragma unroll
        for (int i = 0; i < CI; ++i)
            y[i] = __shfl(s3, i << 3, 64);

        // ---- num[o] = sum_i y[i] * W[i][o]  (W via scalar cache / SGPRs) ----
        #pragma unroll
        for (int o = 0; o < CO; ++o) num[o] = 0.f;
        #pragma unroll
        for (int i = 0; i < CI; ++i) {
            const float yi = y[i];
            #pragma unroll
            for (int o = 0; o < CO; ++o)
                num[o] = fmaf(yi, Wg[i * CO + o], num[o]);
        }

        const float inv = 1.0f / den;

        // ---- SCALE FIRST (overflow-safe), then squash ----
        #pragma unroll
        for (int o = 0; o < CO; ++o) num[o] *= inv;

        float nsq = 0.f;
        #pragma unroll
        for (int o = 0; o < CO; ++o) nsq = fmaf(num[o], num[o], nsq);
        const float nrm = sqrtf(nsq);
        ks = nrm / (1.0f + nsq);             // v[o] = num[o] * ks

        // ---- logit[k] += (xs[k] . Wv) * ks, Wv[i] = sum_o W[i][o]*num[o] ----
        if (iter < 2) {
            float wv[CI];
            #pragma unroll
            for (int i = 0; i < CI; ++i) {
                float d0 = 0.f, d1 = 0.f;
                #pragma unroll
                for (int o = 0; o < CO; o += 2) {
                    d0 = fmaf(Wg[i * CO + o],     num[o],     d0);
                    d1 = fmaf(Wg[i * CO + o + 1], num[o + 1], d1);
                }
                wv[i] = d0 + d1;
            }
            #pragma unroll
            for (int k = 0; k < RPT; ++k) {
                float d = 0.f;
                #pragma unroll
                for (int i = 0; i < CI; ++i) d = fmaf(xs[k][i], wv[i], d);
                logit[k] = fmaf(d, ks, logit[k]);
            }
        }
    }

    // ---- write v = num * ks: 4 lanes store one float4 each ----
    if (t < 4) {
        float4* op = (float4*)(out + ((size_t)b * NC + c) * CO);
        op[t] = make_float4(num[4*t+0]*ks, num[4*t+1]*ks,
                            num[4*t+2]*ks, num[4*t+3]*ks);
    }
}

extern "C" void kernel_launch(void* const* d_in, const int* in_sizes, int n_in,
                              void* d_out, int out_size, void* d_ws, size_t ws_size,
                              hipStream_t stream) {
    const float* x  = (const float*)d_in[0];   // (512, 512, 8)
    const float* rw = (const float*)d_in[1];   // (10, 512, 8, 16)
    float* out = (float*)d_out;                // (512, 10, 16)

    dim3 grid(BATCH * NC);
    dim3 block(TPB);
    caps_route_kernel<<<grid, block, 0, stream>>>(x, rw, out);
}

// Round 8
// 25.430 us; speedup vs baseline: 1.7262x; 1.7262x over previous
//
#include <hip/hip_runtime.h>
#include <math.h>

// Problem constants (from reference)
constexpr int BATCH = 512;
constexpr int NC    = 10;
constexpr int RR    = 512;   // NUM_ROUTES
constexpr int CI    = 8;     // IN_CHANNELS
constexpr int CO    = 16;    // OUT_CHANNELS

constexpr int TPB = 64;          // ONE wave per block
constexpr int RPT = RR / TPB;    // 8 routes per thread

// ============================================================================
// Kernel 1: G[b,c] = W W^T  (8x8 Gram of route_weights[c, b, :, :])
// One wave per (b,c); lane l computes G[l>>3][l&7].
// ============================================================================
__global__ __launch_bounds__(TPB) void caps_gram_kernel(
    const float* __restrict__ rw,   // (NC, RR, CI, CO)
    float* __restrict__ Gws)        // (BATCH*NC, 64), blk = b*NC + c
{
    const int blk = blockIdx.x;
    const int b   = blk / NC;
    const int c   = blk - b * NC;
    const int t   = threadIdx.x;

    __shared__ __align__(16) float W[CI * CO];
    const float* Wg = rw + ((size_t)c * RR + b) * (CI * CO);
    W[t]      = Wg[t];
    W[t + 64] = Wg[t + 64];
    __syncthreads();

    const int i = t >> 3;
    const int j = t & 7;
    const float4* ri = (const float4*)&W[i * CO];
    const float4* rj = (const float4*)&W[j * CO];
    float acc = 0.f;
    #pragma unroll
    for (int q = 0; q < 4; ++q) {
        float4 a = ri[q], d = rj[q];
        acc = fmaf(a.x, d.x, acc);
        acc = fmaf(a.y, d.y, acc);
        acc = fmaf(a.z, d.z, acc);
        acc = fmaf(a.w, d.w, acc);
    }
    Gws[(size_t)blk * 64 + t] = acc;
}

// ============================================================================
// Kernel 2: routing entirely in x-space via G (W never touched in the loop).
//   z   = softmax-weighted mean of x rows (8-vec, butterfly-reduced)
//   g   = G z           (SGPR-resident G, 64 FMA)
//   nsq = z . g ; ks = sqrt(nsq)/(1+nsq)
//   logit_r += ks * (x_r . g)
// Epilogue (once): v = (z W) * ks, lanes 0..15 each produce one output elem.
// ============================================================================
__global__ __launch_bounds__(TPB) void caps_route_g_kernel(
    const float* __restrict__ x,    // (BATCH, RR, CI)
    const float* __restrict__ rw,   // (NC, RR, CI, CO)
    const float* __restrict__ Gws,  // (BATCH*NC, 64)
    float* __restrict__ out)        // (BATCH, NC, CO)
{
    const int blk = blockIdx.x;          // b*NC + c
    const int b   = blk / NC;
    const int c   = blk - b * NC;
    const int t   = threadIdx.x;         // 0..63 == lane

    // Wave-uniform G pointer -> s_load, 64 floats resident in SGPRs
    const float* __restrict__ G = Gws + (size_t)blk * 64;

    // ---- load x rows (coalesced float4, VMEM) ----
    float xs[RPT][CI];
    #pragma unroll
    for (int k = 0; k < RPT; ++k) {
        const float4* xp = (const float4*)(x + ((size_t)b * RR + t + k * TPB) * CI);
        float4 a0 = xp[0], a1 = xp[1];
        xs[k][0]=a0.x; xs[k][1]=a0.y; xs[k][2]=a0.z; xs[k][3]=a0.w;
        xs[k][4]=a1.x; xs[k][5]=a1.y; xs[k][6]=a1.z; xs[k][7]=a1.w;
    }

    float logit[RPT];
    #pragma unroll
    for (int k = 0; k < RPT; ++k) logit[k] = 0.f;

    float z[CI];       // normalized weighted mean (all lanes)
    float ks = 0.f;    // squash scale

    for (int iter = 0; iter < 3; ++iter) {
        // ---- per-thread e-weighted x sum ----
        float yl[CI];
        float den = 0.f;
        if (iter == 0) {
            #pragma unroll
            for (int i = 0; i < CI; ++i) {
                float a = (xs[0][i] + xs[1][i]) + (xs[2][i] + xs[3][i]);
                float d = (xs[4][i] + xs[5][i]) + (xs[6][i] + xs[7][i]);
                yl[i] = a + d;
            }
        } else {
            float e[RPT];
            #pragma unroll
            for (int k = 0; k < RPT; ++k) e[k] = __expf(logit[k]);  // |logit| bounded
            den = ((e[0] + e[1]) + (e[2] + e[3])) + ((e[4] + e[5]) + (e[6] + e[7]));
            #pragma unroll
            for (int i = 0; i < CI; ++i) {
                float a = fmaf(e[0], xs[0][i], e[1] * xs[1][i]);
                float d = fmaf(e[2], xs[2][i], e[3] * xs[3][i]);
                float f = fmaf(e[4], xs[4][i], e[5] * xs[5][i]);
                float g = fmaf(e[6], xs[6][i], e[7] * xs[7][i]);
                yl[i] = (a + d) + (f + g);
            }
        }

        // ---- value-split butterfly on 8-vector (10 shuffles) ----
        float s1[4];
        {
            const bool hi = (t & 32) != 0;
            #pragma unroll
            for (int k = 0; k < 4; ++k) {
                float keep = hi ? yl[4 + k] : yl[k];
                float send = hi ? yl[k]     : yl[4 + k];
                s1[k] = keep + __shfl_xor(send, 32, 64);
            }
        }
        float s2[2];
        {
            const bool hi = (t & 16) != 0;
            #pragma unroll
            for (int k = 0; k < 2; ++k) {
                float keep = hi ? s1[2 + k] : s1[k];
                float send = hi ? s1[k]     : s1[2 + k];
                s2[k] = keep + __shfl_xor(send, 16, 64);
            }
        }
        float s3;
        {
            const bool hi = (t & 8) != 0;
            float keep = hi ? s2[1] : s2[0];
            float send = hi ? s2[0] : s2[1];
            s3 = keep + __shfl_xor(send, 8, 64);
        }
        s3 += __shfl_xor(s3, 4, 64);
        s3 += __shfl_xor(s3, 2, 64);
        s3 += __shfl_xor(s3, 1, 64);
        // z_raw[e] replicated in lanes 8e..8e+7

        if (iter != 0) {
            den += __shfl_xor(den, 32, 64);
            den += __shfl_xor(den, 16, 64);
            den += __shfl_xor(den,  8, 64);
            den += __shfl_xor(den,  4, 64);
            den += __shfl_xor(den,  2, 64);
            den += __shfl_xor(den,  1, 64);
        } else {
            den = (float)RR;
        }

        // ---- broadcast z_raw, normalize ----
        const float inv = 1.0f / den;
        #pragma unroll
        for (int i = 0; i < CI; ++i)
            z[i] = __shfl(s3, i << 3, 64) * inv;

        // ---- g = G z (G via resident SGPRs), nsq = z.g ----
        float g[CI];
        #pragma unroll
        for (int i = 0; i < CI; ++i) {
            float d0 = fmaf(G[i*8+0], z[0], G[i*8+1] * z[1]);
            float d1 = fmaf(G[i*8+2], z[2], G[i*8+3] * z[3]);
            float d2 = fmaf(G[i*8+4], z[4], G[i*8+5] * z[5]);
            float d3 = fmaf(G[i*8+6], z[6], G[i*8+7] * z[7]);
            g[i] = (d0 + d1) + (d2 + d3);
        }
        float nsq = 0.f;
        #pragma unroll
        for (int i = 0; i < CI; ++i) nsq = fmaf(z[i], g[i], nsq);
        const float nrm = sqrtf(nsq);
        ks = nrm / (1.0f + nsq);

        // ---- logit_k += ks * (xs_k . g) ----
        if (iter < 2) {
            #pragma unroll
            for (int k = 0; k < RPT; ++k) {
                float d = 0.f;
                #pragma unroll
                for (int i = 0; i < CI; ++i) d = fmaf(xs[k][i], g[i], d);
                logit[k] = fmaf(d, ks, logit[k]);
            }
        }
    }

    // ---- epilogue: v[o] = ks * sum_i z[i] * W[i][o]; lanes 0..15 store ----
    if (t < CO) {
        const float* Wg = rw + ((size_t)c * RR + b) * (CI * CO);
        float val = 0.f;
        #pragma unroll
        for (int i = 0; i < CI; ++i)
            val = fmaf(z[i], Wg[i * CO + t], val);   // coalesced 64B per i
        out[((size_t)b * NC + c) * CO + t] = val * ks;
    }
}

// ============================================================================
// Fallback (ws too small): round-6 kernel — W staged in LDS, factored routing.
// ============================================================================
__global__ __launch_bounds__(TPB) void caps_route_lds_kernel(
    const float* __restrict__ x, const float* __restrict__ rw,
    float* __restrict__ out)
{
    const int blk = blockIdx.x;
    const int b   = blk / NC;
    const int c   = blk - b * NC;
    const int t   = threadIdx.x;

    __shared__ __align__(16) float W[CI][CO];
    {
        const size_t base = ((size_t)c * RR + b) * (CI * CO);
        ((float*)W)[t]      = rw[base + t];
        ((float*)W)[t + 64] = rw[base + t + 64];
    }
    __syncthreads();

    float xs[RPT][CI];
    #pragma unroll
    for (int k = 0; k < RPT; ++k) {
        const float4* xp = (const float4*)(x + ((size_t)b * RR + t + k * TPB) * CI);
        float4 a0 = xp[0], a1 = xp[1];
        xs[k][0]=a0.x; xs[k][1]=a0.y; xs[k][2]=a0.z; xs[k][3]=a0.w;
        xs[k][4]=a1.x; xs[k][5]=a1.y; xs[k][6]=a1.z; xs[k][7]=a1.w;
    }

    float logit[RPT];
    #pragma unroll
    for (int k = 0; k < RPT; ++k) logit[k] = 0.f;

    float num[CO];
    float ks = 0.f;

    for (int iter = 0; iter < 3; ++iter) {
        float yl[CI];
        float den = 0.f;
        if (iter == 0) {
            #pragma unroll
            for (int i = 0; i < CI; ++i) {
                float a = (xs[0][i] + xs[1][i]) + (xs[2][i] + xs[3][i]);
                float d = (xs[4][i] + xs[5][i]) + (xs[6][i] + xs[7][i]);
                yl[i] = a + d;
            }
        } else {
            float e[RPT];
            #pragma unroll
            for (int k = 0; k < RPT; ++k) e[k] = __expf(logit[k]);
            den = ((e[0] + e[1]) + (e[2] + e[3])) + ((e[4] + e[5]) + (e[6] + e[7]));
            #pragma unroll
            for (int i = 0; i < CI; ++i) {
                float a = fmaf(e[0], xs[0][i], e[1] * xs[1][i]);
                float d = fmaf(e[2], xs[2][i], e[3] * xs[3][i]);
                float f = fmaf(e[4], xs[4][i], e[5] * xs[5][i]);
                float g = fmaf(e[6], xs[6][i], e[7] * xs[7][i]);
                yl[i] = (a + d) + (f + g);
            }
        }

        float s1[4];
        {
            const bool hi = (t & 32) != 0;
            #pragma unroll
            for (int k = 0; k < 4; ++k) {
                float keep = hi ? yl[4 + k] : yl[k];
                float send = hi ? yl[k]     : yl[4 + k];
                s1[k] = keep + __shfl_xor(send, 32, 64);
            }
        }
        float s2[2];
        {
            const bool hi = (t & 16) != 0;
            #pragma unroll
            for (int k = 0; k < 2; ++k) {
                float keep = hi ? s1[2 + k] : s1[k];
                float send = hi ? s1[k]     : s1[2 + k];
                s2[k] = keep + __shfl_xor(send, 16, 64);
            }
        }
        float s3;
        {
            const bool hi = (t & 8) != 0;
            float keep = hi ? s2[1] : s2[0];
            float send = hi ? s2[0] : s2[1];
            s3 = keep + __shfl_xor(send, 8, 64);
        }
        s3 += __shfl_xor(s3, 4, 64);
        s3 += __shfl_xor(s3, 2, 64);
        s3 += __shfl_xor(s3, 1, 64);

        if (iter != 0) {
            den += __shfl_xor(den, 32, 64);
            den += __shfl_xor(den, 16, 64);
            den += __shfl_xor(den,  8, 64);
            den += __shfl_xor(den,  4, 64);
            den += __shfl_xor(den,  2, 64);
            den += __shfl_xor(den,  1, 64);
        } else {
            den = (float)RR;
        }

        float y[CI];
        #pragma unroll
        for (int i = 0; i < CI; ++i)
            y[i] = __shfl(s3, i << 3, 64);

        {
            float4 a0 = make_float4(0.f,0.f,0.f,0.f);
            float4 a1 = a0, a2 = a0, a3 = a0;
            #pragma unroll
            for (int i = 0; i < CI; ++i) {
                const float4* Wr = (const float4*)&W[i][0];
                float4 w0 = Wr[0], w1 = Wr[1], w2 = Wr[2], w3 = Wr[3];
                const float yi = y[i];
                a0.x = fmaf(yi, w0.x, a0.x); a0.y = fmaf(yi, w0.y, a0.y);
                a0.z = fmaf(yi, w0.z, a0.z); a0.w = fmaf(yi, w0.w, a0.w);
                a1.x = fmaf(yi, w1.x, a1.x); a1.y = fmaf(yi, w1.y, a1.y);
                a1.z = fmaf(yi, w1.z, a1.z); a1.w = fmaf(yi, w1.w, a1.w);
                a2.x = fmaf(yi, w2.x, a2.x); a2.y = fmaf(yi, w2.y, a2.y);
                a2.z = fmaf(yi, w2.z, a2.z); a2.w = fmaf(yi, w2.w, a2.w);
                a3.x = fmaf(yi, w3.x, a3.x); a3.y = fmaf(yi, w3.y, a3.y);
                a3.z = fmaf(yi, w3.z, a3.z); a3.w = fmaf(yi, w3.w, a3.w);
            }
            num[0]=a0.x; num[1]=a0.y; num[2]=a0.z; num[3]=a0.w;
            num[4]=a1.x; num[5]=a1.y; num[6]=a1.z; num[7]=a1.w;
            num[8]=a2.x; num[9]=a2.y; num[10]=a2.z; num[11]=a2.w;
            num[12]=a3.x; num[13]=a3.y; num[14]=a3.z; num[15]=a3.w;
        }

        const float inv = 1.0f / den;
        #pragma unroll
        for (int o = 0; o < CO; ++o) num[o] *= inv;

        float nsq = 0.f;
        #pragma unroll
        for (int o = 0; o < CO; ++o) nsq = fmaf(num[o], num[o], nsq);
        const float nrm = sqrtf(nsq);
        ks = nrm / (1.0f + nsq);

        if (iter < 2) {
            float wv[CI];
            #pragma unroll
            for (int i = 0; i < CI; ++i) {
                const float4* Wr = (const float4*)&W[i][0];
                float4 w0 = Wr[0], w1 = Wr[1], w2 = Wr[2], w3 = Wr[3];
                float d0 = fmaf(w0.x, num[0],  w0.y * num[1]);
                float d1 = fmaf(w0.z, num[2],  w0.w * num[3]);
                float d2 = fmaf(w1.x, num[4],  w1.y * num[5]);
                float d3 = fmaf(w1.z, num[6],  w1.w * num[7]);
                float d4 = fmaf(w2.x, num[8],  w2.y * num[9]);
                float d5 = fmaf(w2.z, num[10], w2.w * num[11]);
                float d6 = fmaf(w3.x, num[12], w3.y * num[13]);
                float d7 = fmaf(w3.z, num[14], w3.w * num[15]);
                wv[i] = ((d0 + d1) + (d2 + d3)) + ((d4 + d5) + (d6 + d7));
            }
            #pragma unroll
            for (int k = 0; k < RPT; ++k) {
                float d = 0.f;
                #pragma unroll
                for (int i = 0; i < CI; ++i) d = fmaf(xs[k][i], wv[i], d);
                logit[k] = fmaf(d, ks, logit[k]);
            }
        }
    }

    if (t < 4) {
        float4* op = (float4*)(out + ((size_t)b * NC + c) * CO);
        op[t] = make_float4(num[4*t+0]*ks, num[4*t+1]*ks,
                            num[4*t+2]*ks, num[4*t+3]*ks);
    }
}

extern "C" void kernel_launch(void* const* d_in, const int* in_sizes, int n_in,
                              void* d_out, int out_size, void* d_ws, size_t ws_size,
                              hipStream_t stream) {
    const float* x  = (const float*)d_in[0];   // (512, 512, 8)
    const float* rw = (const float*)d_in[1];   // (10, 512, 8, 16)
    float* out = (float*)d_out;                // (512, 10, 16)

    const size_t g_bytes = (size_t)BATCH * NC * 64 * sizeof(float);  // 1.31 MB
    dim3 grid(BATCH * NC);
    dim3 block(TPB);

    if (ws_size >= g_bytes) {
        float* Gws = (float*)d_ws;
        caps_gram_kernel<<<grid, block, 0, stream>>>(rw, Gws);
        caps_route_g_kernel<<<grid, block, 0, stream>>>(x, rw, Gws, out);
    } else {
        caps_route_lds_kernel<<<grid, block, 0, stream>>>(x, rw, out);
    }
}

// Round 9
// 25.361 us; speedup vs baseline: 1.7308x; 1.0027x over previous
//
#include <hip/hip_runtime.h>
#include <math.h>

// Problem constants (from reference)
constexpr int BATCH = 512;
constexpr int NC    = 10;
constexpr int RR    = 512;   // NUM_ROUTES
constexpr int CI    = 8;     // IN_CHANNELS
constexpr int CO    = 16;    // OUT_CHANNELS

constexpr int TPB   = 64;          // ONE wave per block
constexpr int RPT   = RR / TPB;    // 8 routes per thread
constexpr int NPAIR = NC / 2;      // 2 capsules per wave

// One wave per (b, capsule-pair). Thread t owns routes t + k*64.
// u_hat[b,c,r,o] = sum_i x[b,r,i] * route_weights[c, b, i, o]
//   (weight's R-slot indexed by b — the reference's broadcasting quirk)
//
// h-form routing (u_hat AND per-route logits eliminated):
//   logit_r = x_r . H,  H = sum_m ks_m g_m,  g = G z,  G = W W^T (8x8)
//   z = (sum_r e_r x_r) / (sum_r e_r),  e_r = exp(x_r . H)
//   ks = |s|/(1+|s|^2) with |s|^2 = z . G z
//   output v = (z W) * ks
// Two capsules of the same b share xs; ONE 16-value butterfly reduces both.
__global__ __launch_bounds__(TPB) void caps_pair_kernel(
    const float* __restrict__ x,    // (BATCH, RR, CI)
    const float* __restrict__ rw,   // (NC, RR, CI, CO)
    float* __restrict__ out)        // (BATCH, NC, CO)
{
    const int blk = blockIdx.x;          // 0 .. BATCH*NPAIR-1
    const int b   = blk / NPAIR;
    const int cp  = blk - b * NPAIR;
    const int c0  = cp * 2;              // capsules c0, c0+1
    const int t   = threadIdx.x;         // 0..63 == lane

    __shared__ __align__(16) float Wsh[2][CI * CO];  // 1 KiB
    __shared__ __align__(16) float Gsh[2][CI * CI];  // 512 B

    // ---- stage W for both capsules (4 coalesced floats per thread) ----
    {
        const float* W0 = rw + ((size_t)c0 * RR + b) * (CI * CO);
        const float* W1 = rw + ((size_t)(c0 + 1) * RR + b) * (CI * CO);
        Wsh[0][t] = W0[t];  Wsh[0][t + 64] = W0[t + 64];
        Wsh[1][t] = W1[t];  Wsh[1][t + 64] = W1[t + 64];
    }
    __syncthreads();

    // ---- G = W W^T for both capsules: lane t computes entries 2t, 2t+1 ----
    {
        #pragma unroll
        for (int u = 0; u < 2; ++u) {
            const int e  = 2 * t + u;
            const int cc = e >> 6, rem = e & 63, i = rem >> 3, j = rem & 7;
            const float4* ri = (const float4*)&Wsh[cc][i * CO];
            const float4* rj = (const float4*)&Wsh[cc][j * CO];
            float acc = 0.f;
            #pragma unroll
            for (int q = 0; q < 4; ++q) {
                float4 a = ri[q], d = rj[q];
                acc = fmaf(a.x, d.x, acc);
                acc = fmaf(a.y, d.y, acc);
                acc = fmaf(a.z, d.z, acc);
                acc = fmaf(a.w, d.w, acc);
            }
            Gsh[cc][rem] = acc;
        }
    }
    __syncthreads();

    // ---- load x rows (coalesced float4, VMEM) ----
    float xs[RPT][CI];
    #pragma unroll
    for (int k = 0; k < RPT; ++k) {
        const float4* xp = (const float4*)(x + ((size_t)b * RR + t + k * TPB) * CI);
        float4 a0 = xp[0], a1 = xp[1];
        xs[k][0]=a0.x; xs[k][1]=a0.y; xs[k][2]=a0.z; xs[k][3]=a0.w;
        xs[k][4]=a1.x; xs[k][5]=a1.y; xs[k][6]=a1.z; xs[k][7]=a1.w;
    }

    float H0[CI], H1[CI];
    #pragma unroll
    for (int i = 0; i < CI; ++i) { H0[i] = 0.f; H1[i] = 0.f; }

    float z0[CI], z1[CI];
    float ks0 = 0.f, ks1 = 0.f;

    for (int iter = 0; iter < 3; ++iter) {
        if (iter == 0) {
            // ---- H = 0 -> softmax uniform, z shared by both capsules ----
            float yl[CI];
            #pragma unroll
            for (int i = 0; i < CI; ++i) {
                float a = (xs[0][i] + xs[1][i]) + (xs[2][i] + xs[3][i]);
                float d = (xs[4][i] + xs[5][i]) + (xs[6][i] + xs[7][i]);
                yl[i] = a + d;
            }
            // 8-vec value-split butterfly (10 shuffles)
            float s1[4];
            {
                const bool hi = (t & 32) != 0;
                #pragma unroll
                for (int k = 0; k < 4; ++k) {
                    float keep = hi ? yl[4 + k] : yl[k];
                    float send = hi ? yl[k]     : yl[4 + k];
                    s1[k] = keep + __shfl_xor(send, 32, 64);
                }
            }
            float s2[2];
            {
                const bool hi = (t & 16) != 0;
                #pragma unroll
                for (int k = 0; k < 2; ++k) {
                    float keep = hi ? s1[2 + k] : s1[k];
                    float send = hi ? s1[k]     : s1[2 + k];
                    s2[k] = keep + __shfl_xor(send, 16, 64);
                }
            }
            float s3;
            {
                const bool hi = (t & 8) != 0;
                float keep = hi ? s2[1] : s2[0];
                float send = hi ? s2[0] : s2[1];
                s3 = keep + __shfl_xor(send, 8, 64);
            }
            s3 += __shfl_xor(s3, 4, 64);
            s3 += __shfl_xor(s3, 2, 64);
            s3 += __shfl_xor(s3, 1, 64);

            const float inv = 1.0f / (float)RR;
            #pragma unroll
            for (int i = 0; i < CI; ++i) {
                const float zi = __shfl(s3, i << 3, 64) * inv;
                z0[i] = zi; z1[i] = zi;
            }
        } else {
            // ---- e = exp(x.H), accumulate weighted sums for BOTH capsules ----
            float p[16];
            #pragma unroll
            for (int j = 0; j < 16; ++j) p[j] = 0.f;
            float dA = 0.f, dB = 0.f;
            #pragma unroll
            for (int k = 0; k < RPT; ++k) {
                float sA = 0.f, sB = 0.f;
                #pragma unroll
                for (int i = 0; i < CI; ++i) {
                    sA = fmaf(xs[k][i], H0[i], sA);
                    sB = fmaf(xs[k][i], H1[i], sB);
                }
                const float eA = __expf(sA);   // |logit| bounded (<~44)
                const float eB = __expf(sB);
                dA += eA; dB += eB;
                #pragma unroll
                for (int i = 0; i < CI; ++i) {
                    p[i]     = fmaf(eA, xs[k][i], p[i]);
                    p[8 + i] = fmaf(eB, xs[k][i], p[8 + i]);
                }
            }

            // ---- 16-value value-split butterfly (17 shuffles, verified) ----
            float q1[8];
            {
                const bool hi = (t & 32) != 0;
                #pragma unroll
                for (int k = 0; k < 8; ++k) {
                    float keep = hi ? p[8 + k] : p[k];
                    float send = hi ? p[k]     : p[8 + k];
                    q1[k] = keep + __shfl_xor(send, 32, 64);
                }
            }
            float q2[4];
            {
                const bool hi = (t & 16) != 0;
                #pragma unroll
                for (int k = 0; k < 4; ++k) {
                    float keep = hi ? q1[4 + k] : q1[k];
                    float send = hi ? q1[k]     : q1[4 + k];
                    q2[k] = keep + __shfl_xor(send, 16, 64);
                }
            }
            float q3[2];
            {
                const bool hi = (t & 8) != 0;
                #pragma unroll
                for (int k = 0; k < 2; ++k) {
                    float keep = hi ? q2[2 + k] : q2[k];
                    float send = hi ? q2[k]     : q2[2 + k];
                    q3[k] = keep + __shfl_xor(send, 8, 64);
                }
            }
            float q4;
            {
                const bool hi = (t & 4) != 0;
                float keep = hi ? q3[1] : q3[0];
                float send = hi ? q3[0] : q3[1];
                q4 = keep + __shfl_xor(send, 4, 64);
            }
            q4 += __shfl_xor(q4, 2, 64);
            q4 += __shfl_xor(q4, 1, 64);
            // element j=(lane>>2)&15 fully reduced; j = cap*8 + i

            // ---- 2-value den butterfly (6 shuffles + 2 broadcasts) ----
            float dq;
            {
                const bool hiB = (t & 32) != 0;
                float keep = hiB ? dB : dA;
                float send = hiB ? dA : dB;
                dq = keep + __shfl_xor(send, 32, 64);
            }
            dq += __shfl_xor(dq, 16, 64);
            dq += __shfl_xor(dq,  8, 64);
            dq += __shfl_xor(dq,  4, 64);
            dq += __shfl_xor(dq,  2, 64);
            dq += __shfl_xor(dq,  1, 64);
            const float invA = 1.0f / __shfl(dq, 0, 64);
            const float invB = 1.0f / __shfl(dq, 32, 64);

            // ---- broadcast + scale-first (overflow-safe) ----
            #pragma unroll
            for (int i = 0; i < CI; ++i) {
                z0[i] = __shfl(q4, i << 2, 64)       * invA;
                z1[i] = __shfl(q4, (8 + i) << 2, 64) * invB;
            }
        }

        // ---- g = G z (uniform-address LDS reads -> broadcast) ----
        float g0[CI], g1[CI];
        #pragma unroll
        for (int i = 0; i < CI; ++i) {
            const float4* Ga = (const float4*)&Gsh[0][i * CI];
            const float4* Gb = (const float4*)&Gsh[1][i * CI];
            float4 a0 = Ga[0], a1 = Ga[1];
            float4 b0 = Gb[0], b1 = Gb[1];
            float u0 = fmaf(a0.x, z0[0], a0.y * z0[1]);
            float u1 = fmaf(a0.z, z0[2], a0.w * z0[3]);
            float u2 = fmaf(a1.x, z0[4], a1.y * z0[5]);
            float u3 = fmaf(a1.z, z0[6], a1.w * z0[7]);
            g0[i] = (u0 + u1) + (u2 + u3);
            float v0 = fmaf(b0.x, z1[0], b0.y * z1[1]);
            float v1 = fmaf(b0.z, z1[2], b0.w * z1[3]);
            float v2 = fmaf(b1.x, z1[4], b1.y * z1[5]);
            float v3 = fmaf(b1.z, z1[6], b1.w * z1[7]);
            g1[i] = (v0 + v1) + (v2 + v3);
        }

        // ---- nsq = z.g ; ks = sqrt(nsq)/(1+nsq) ----
        float n0 = 0.f, n1 = 0.f;
        #pragma unroll
        for (int i = 0; i < CI; ++i) {
            n0 = fmaf(z0[i], g0[i], n0);
            n1 = fmaf(z1[i], g1[i], n1);
        }
        ks0 = sqrtf(n0) / (1.0f + n0);
        ks1 = sqrtf(n1) / (1.0f + n1);

        // ---- H += ks * g (skip on last iter) ----
        if (iter < 2) {
            #pragma unroll
            for (int i = 0; i < CI; ++i) {
                H0[i] = fmaf(ks0, g0[i], H0[i]);
                H1[i] = fmaf(ks1, g1[i], H1[i]);
            }
        }
    }

    // ---- epilogue: v[o] = ks * sum_i z[i] * W[i][o] (W from LDS) ----
    if (t < CO) {
        float val = 0.f;
        #pragma unroll
        for (int i = 0; i < CI; ++i)
            val = fmaf(z0[i], Wsh[0][i * CO + t], val);
        out[((size_t)b * NC + c0) * CO + t] = val * ks0;
    } else if (t >= 32 && t < 32 + CO) {
        const int o = t - 32;
        float val = 0.f;
        #pragma unroll
        for (int i = 0; i < CI; ++i)
            val = fmaf(z1[i], Wsh[1][i * CO + o], val);
        out[((size_t)b * NC + (c0 + 1)) * CO + o] = val * ks1;
    }
}

extern "C" void kernel_launch(void* const* d_in, const int* in_sizes, int n_in,
                              void* d_out, int out_size, void* d_ws, size_t ws_size,
                              hipStream_t stream) {
    const float* x  = (const float*)d_in[0];   // (512, 512, 8)
    const float* rw = (const float*)d_in[1];   // (10, 512, 8, 16)
    float* out = (float*)d_out;                // (512, 10, 16)

    dim3 grid(BATCH * NPAIR);   // 2560 blocks, one wave each
    dim3 block(TPB);
    caps_pair_kernel<<<grid, block, 0, stream>>>(x, rw, out);
}

// Round 10
// 24.820 us; speedup vs baseline: 1.7686x; 1.0218x over previous
//
#include <hip/hip_runtime.h>
#include <math.h>

// Problem constants (from reference)
constexpr int BATCH = 512;
constexpr int NC    = 10;
constexpr int RR    = 512;   // NUM_ROUTES
constexpr int CI    = 8;     // IN_CHANNELS
constexpr int CO    = 16;    // OUT_CHANNELS

constexpr int NPAIR = NC / 2;      // capsule pairs
constexpr int TPB   = 64 * NPAIR;  // 320 threads = 5 waves, one pair per wave
constexpr int RPT   = RR / 64;     // 8 routes per thread

// One block per b; wave w handles capsules (2w, 2w+1). All 5 waves read the
// same 16 KB x-slab with identical per-lane addresses -> L1-resident after
// wave 0 warms it (x fetched ~once per b from HBM instead of 5x).
//
// u_hat[b,c,r,o] = sum_i x[b,r,i] * route_weights[c, b, i, o]
//   (weight's R-slot indexed by b — the reference's broadcasting quirk)
//
// h-form routing (u_hat AND per-route logits eliminated):
//   logit_r = x_r . H,  H = sum_m ks_m g_m,  g = G z,  G = W W^T (8x8)
//   z = (sum_r e_r x_r) / (sum_r e_r),  e_r = exp(x_r . H)
//   ks = |s|/(1+|s|^2) with |s|^2 = z . G z
//   output v = (z W) * ks
__global__ __launch_bounds__(TPB) void caps_block_kernel(
    const float* __restrict__ x,    // (BATCH, RR, CI)
    const float* __restrict__ rw,   // (NC, RR, CI, CO)
    float* __restrict__ out)        // (BATCH, NC, CO)
{
    const int b    = blockIdx.x;         // 0 .. BATCH-1
    const int t    = threadIdx.x;        // 0..319
    const int wv   = t >> 6;             // 0..4  (capsule pair)
    const int lane = t & 63;
    const int c0   = wv * 2;             // capsules c0, c0+1

    __shared__ __align__(16) float Wsh[NPAIR][2][CI * CO];  // 5 KiB
    __shared__ __align__(16) float Gsh[NPAIR][2][CI * CI];  // 2.5 KiB

    // ---- each wave stages W for its two capsules (coalesced) ----
    {
        const float* W0 = rw + ((size_t)c0 * RR + b) * (CI * CO);
        const float* W1 = rw + ((size_t)(c0 + 1) * RR + b) * (CI * CO);
        Wsh[wv][0][lane] = W0[lane];  Wsh[wv][0][lane + 64] = W0[lane + 64];
        Wsh[wv][1][lane] = W1[lane];  Wsh[wv][1][lane + 64] = W1[lane + 64];
    }
    __syncthreads();

    // ---- G = W W^T for both capsules: lane computes entries 2*lane, 2*lane+1 ----
    {
        #pragma unroll
        for (int u = 0; u < 2; ++u) {
            const int e  = 2 * lane + u;
            const int cc = e >> 6, rem = e & 63, i = rem >> 3, j = rem & 7;
            const float4* ri = (const float4*)&Wsh[wv][cc][i * CO];
            const float4* rj = (const float4*)&Wsh[wv][cc][j * CO];
            float acc = 0.f;
            #pragma unroll
            for (int q = 0; q < 4; ++q) {
                float4 a = ri[q], d = rj[q];
                acc = fmaf(a.x, d.x, acc);
                acc = fmaf(a.y, d.y, acc);
                acc = fmaf(a.z, d.z, acc);
                acc = fmaf(a.w, d.w, acc);
            }
            Gsh[wv][cc][rem] = acc;
        }
    }
    __syncthreads();

    // ---- load x rows (coalesced float4; L1-shared across the 5 waves) ----
    float xs[RPT][CI];
    #pragma unroll
    for (int k = 0; k < RPT; ++k) {
        const float4* xp = (const float4*)(x + ((size_t)b * RR + lane + k * 64) * CI);
        float4 a0 = xp[0], a1 = xp[1];
        xs[k][0]=a0.x; xs[k][1]=a0.y; xs[k][2]=a0.z; xs[k][3]=a0.w;
        xs[k][4]=a1.x; xs[k][5]=a1.y; xs[k][6]=a1.z; xs[k][7]=a1.w;
    }

    float H0[CI], H1[CI];
    #pragma unroll
    for (int i = 0; i < CI; ++i) { H0[i] = 0.f; H1[i] = 0.f; }

    float z0[CI], z1[CI];
    float ks0 = 0.f, ks1 = 0.f;

    for (int iter = 0; iter < 3; ++iter) {
        if (iter == 0) {
            // ---- H = 0 -> softmax uniform, z shared by both capsules ----
            float yl[CI];
            #pragma unroll
            for (int i = 0; i < CI; ++i) {
                float a = (xs[0][i] + xs[1][i]) + (xs[2][i] + xs[3][i]);
                float d = (xs[4][i] + xs[5][i]) + (xs[6][i] + xs[7][i]);
                yl[i] = a + d;
            }
            // 8-vec value-split butterfly (10 shuffles)
            float s1[4];
            {
                const bool hi = (lane & 32) != 0;
                #pragma unroll
                for (int k = 0; k < 4; ++k) {
                    float keep = hi ? yl[4 + k] : yl[k];
                    float send = hi ? yl[k]     : yl[4 + k];
                    s1[k] = keep + __shfl_xor(send, 32, 64);
                }
            }
            float s2[2];
            {
                const bool hi = (lane & 16) != 0;
                #pragma unroll
                for (int k = 0; k < 2; ++k) {
                    float keep = hi ? s1[2 + k] : s1[k];
                    float send = hi ? s1[k]     : s1[2 + k];
                    s2[k] = keep + __shfl_xor(send, 16, 64);
                }
            }
            float s3;
            {
                const bool hi = (lane & 8) != 0;
                float keep = hi ? s2[1] : s2[0];
                float send = hi ? s2[0] : s2[1];
                s3 = keep + __shfl_xor(send, 8, 64);
            }
            s3 += __shfl_xor(s3, 4, 64);
            s3 += __shfl_xor(s3, 2, 64);
            s3 += __shfl_xor(s3, 1, 64);

            const float inv = 1.0f / (float)RR;
            #pragma unroll
            for (int i = 0; i < CI; ++i) {
                const float zi = __shfl(s3, i << 3, 64) * inv;
                z0[i] = zi; z1[i] = zi;
            }
        } else {
            // ---- e = exp(x.H), weighted sums for BOTH capsules ----
            float p[16];
            #pragma unroll
            for (int j = 0; j < 16; ++j) p[j] = 0.f;
            float dA = 0.f, dB = 0.f;
            #pragma unroll
            for (int k = 0; k < RPT; ++k) {
                float sA = 0.f, sB = 0.f;
                #pragma unroll
                for (int i = 0; i < CI; ++i) {
                    sA = fmaf(xs[k][i], H0[i], sA);
                    sB = fmaf(xs[k][i], H1[i], sB);
                }
                const float eA = __expf(sA);   // |logit| bounded (<~44)
                const float eB = __expf(sB);
                dA += eA; dB += eB;
                #pragma unroll
                for (int i = 0; i < CI; ++i) {
                    p[i]     = fmaf(eA, xs[k][i], p[i]);
                    p[8 + i] = fmaf(eB, xs[k][i], p[8 + i]);
                }
            }

            // ---- 16-value value-split butterfly (17 shuffles) ----
            float q1[8];
            {
                const bool hi = (lane & 32) != 0;
                #pragma unroll
                for (int k = 0; k < 8; ++k) {
                    float keep = hi ? p[8 + k] : p[k];
                    float send = hi ? p[k]     : p[8 + k];
                    q1[k] = keep + __shfl_xor(send, 32, 64);
                }
            }
            float q2[4];
            {
                const bool hi = (lane & 16) != 0;
                #pragma unroll
                for (int k = 0; k < 4; ++k) {
                    float keep = hi ? q1[4 + k] : q1[k];
                    float send = hi ? q1[k]     : q1[4 + k];
                    q2[k] = keep + __shfl_xor(send, 16, 64);
                }
            }
            float q3[2];
            {
                const bool hi = (lane & 8) != 0;
                #pragma unroll
                for (int k = 0; k < 2; ++k) {
                    float keep = hi ? q2[2 + k] : q2[k];
                    float send = hi ? q2[k]     : q2[2 + k];
                    q3[k] = keep + __shfl_xor(send, 8, 64);
                }
            }
            float q4;
            {
                const bool hi = (lane & 4) != 0;
                float keep = hi ? q3[1] : q3[0];
                float send = hi ? q3[0] : q3[1];
                q4 = keep + __shfl_xor(send, 4, 64);
            }
            q4 += __shfl_xor(q4, 2, 64);
            q4 += __shfl_xor(q4, 1, 64);
            // element j=(lane>>2)&15 fully reduced; j = cap*8 + i

            // ---- 2-value den butterfly ----
            float dq;
            {
                const bool hiB = (lane & 32) != 0;
                float keep = hiB ? dB : dA;
                float send = hiB ? dA : dB;
                dq = keep + __shfl_xor(send, 32, 64);
            }
            dq += __shfl_xor(dq, 16, 64);
            dq += __shfl_xor(dq,  8, 64);
            dq += __shfl_xor(dq,  4, 64);
            dq += __shfl_xor(dq,  2, 64);
            dq += __shfl_xor(dq,  1, 64);
            const float invA = 1.0f / __shfl(dq, 0, 64);
            const float invB = 1.0f / __shfl(dq, 32, 64);

            // ---- broadcast + scale-first (overflow-safe) ----
            #pragma unroll
            for (int i = 0; i < CI; ++i) {
                z0[i] = __shfl(q4, i << 2, 64)       * invA;
                z1[i] = __shfl(q4, (8 + i) << 2, 64) * invB;
            }
        }

        // ---- g = G z (uniform-address LDS reads -> broadcast) ----
        float g0[CI], g1[CI];
        #pragma unroll
        for (int i = 0; i < CI; ++i) {
            const float4* Ga = (const float4*)&Gsh[wv][0][i * CI];
            const float4* Gb = (const float4*)&Gsh[wv][1][i * CI];
            float4 a0 = Ga[0], a1 = Ga[1];
            float4 b0 = Gb[0], b1 = Gb[1];
            float u0 = fmaf(a0.x, z0[0], a0.y * z0[1]);
            float u1 = fmaf(a0.z, z0[2], a0.w * z0[3]);
            float u2 = fmaf(a1.x, z0[4], a1.y * z0[5]);
            float u3 = fmaf(a1.z, z0[6], a1.w * z0[7]);
            g0[i] = (u0 + u1) + (u2 + u3);
            float v0 = fmaf(b0.x, z1[0], b0.y * z1[1]);
            float v1 = fmaf(b0.z, z1[2], b0.w * z1[3]);
            float v2 = fmaf(b1.x, z1[4], b1.y * z1[5]);
            float v3 = fmaf(b1.z, z1[6], b1.w * z1[7]);
            g1[i] = (v0 + v1) + (v2 + v3);
        }

        // ---- nsq = z.g ; ks = sqrt(nsq)/(1+nsq) ----
        float n0 = 0.f, n1 = 0.f;
        #pragma unroll
        for (int i = 0; i < CI; ++i) {
            n0 = fmaf(z0[i], g0[i], n0);
            n1 = fmaf(z1[i], g1[i], n1);
        }
        ks0 = sqrtf(n0) / (1.0f + n0);
        ks1 = sqrtf(n1) / (1.0f + n1);

        // ---- H += ks * g (skip on last iter) ----
        if (iter < 2) {
            #pragma unroll
            for (int i = 0; i < CI; ++i) {
                H0[i] = fmaf(ks0, g0[i], H0[i]);
                H1[i] = fmaf(ks1, g1[i], H1[i]);
            }
        }
    }

    // ---- epilogue: v[o] = ks * sum_i z[i] * W[i][o] (W from LDS) ----
    if (lane < CO) {
        float val = 0.f;
        #pragma unroll
        for (int i = 0; i < CI; ++i)
            val = fmaf(z0[i], Wsh[wv][0][i * CO + lane], val);
        out[((size_t)b * NC + c0) * CO + lane] = val * ks0;
    } else if (lane >= 32 && lane < 32 + CO) {
        const int o = lane - 32;
        float val = 0.f;
        #pragma unroll
        for (int i = 0; i < CI; ++i)
            val = fmaf(z1[i], Wsh[wv][1][i * CO + o], val);
        out[((size_t)b * NC + (c0 + 1)) * CO + o] = val * ks1;
    }
}

extern "C" void kernel_launch(void* const* d_in, const int* in_sizes, int n_in,
                              void* d_out, int out_size, void* d_ws, size_t ws_size,
                              hipStream_t stream) {
    const float* x  = (const float*)d_in[0];   // (512, 512, 8)
    const float* rw = (const float*)d_in[1];   // (10, 512, 8, 16)
    float* out = (float*)d_out;                // (512, 10, 16)

    dim3 grid(BATCH);       // one block per b
    dim3 block(TPB);        // 5 waves, one capsule pair each
    caps_block_kernel<<<grid, block, 0, stream>>>(x, rw, out);
}